// Round 13
// baseline (502.754 us; speedup 1.0000x reference)
//
#include <hip/hip_runtime.h>
#include <hip/hip_cooperative_groups.h>

namespace cg = cooperative_groups;

#define NN 50000
#define NE 800000
#define NT (NE / 32)

// workspace layout
#define CNT_OFF   0u         // 50000 u32
#define BASE_OFF  204800u    // 50001 u32
#define PART_OFF  409600u    // 196 u32 scan partials
#define SLOT_OFF  417792u    // 800000 u32 per-edge slot
#define SRCW_OFF  3670016u   // 800000 uint2 {src|tgt<<16, w}
#define M_OFF     (1u << 24) // partial max key rows: NE x 64 u16 (sparse-touched)
#define PB 196               // scan blocks: 196*256 >= NN

typedef __bf16 bf16x8 __attribute__((ext_vector_type(8)));
typedef float f32x16 __attribute__((ext_vector_type(16)));
typedef unsigned short u16x2 __attribute__((ext_vector_type(2)));

union U4 { unsigned u[4]; __bf16 h[8]; bf16x8 v; };
union PKU { unsigned u; u16x2 v; };

__device__ __forceinline__ unsigned pkpair(float a, float b) {
  union { unsigned u; __bf16 h[2]; } r;
  r.h[0] = (__bf16)a; r.h[1] = (__bf16)b;
  return r.u;
}
__device__ __forceinline__ float bflo(unsigned u) { return __uint_as_float(u << 16); }
__device__ __forceinline__ float bfhi(unsigned u) { return __uint_as_float(u & 0xFFFF0000u); }
__device__ __forceinline__ unsigned pkmaxu16(unsigned a, unsigned b) {
  PKU x, y, r; x.u = a; y.u = b;
  r.v = __builtin_elementwise_max(x.v, y.v);  // v_pk_max_u16
  return r.u;
}

// =========================== shared device helpers ===========================

__device__ __forceinline__ void stage_weights(const float* __restrict__ w1,
                                              const float* __restrict__ w2,
                                              const float* __restrict__ w3,
                                              unsigned* lds_w, int tid, int bsz) {
  for (int s = tid; s < 1024; s += bsz) {
    const int F = s >> 6, L = s & 63;
    const int t = F >> 1, mt = F & 1;
    const int gg = L >> 5, o = (L & 31) + 32 * mt;
    const float* p = w1 + o * 128 + 16 * t + 8 * gg;
    unsigned* d = &lds_w[(unsigned)(F * 64 + L) * 4u];
    d[0] = pkpair(p[0], p[1]); d[1] = pkpair(p[2], p[3]);
    d[2] = pkpair(p[4], p[5]); d[3] = pkpair(p[6], p[7]);
  }
  for (int s = tid; s < 1024; s += bsz) {
    const int which = s >> 9, r = s & 511;
    const int F = r >> 6, L = r & 63;
    const int t = F >> 1, mt = F & 1;
    const int gg = L >> 5, o = (L & 31) + 32 * mt;
    const float* W = which ? w3 : w2;
    const float* p = W + o * 64 + 16 * t + 4 * gg;
    unsigned* d = &lds_w[(unsigned)((16 + which * 8 + F) * 64 + L) * 4u];
    d[0] = pkpair(p[0], p[1]); d[1] = pkpair(p[2], p[3]);
    d[2] = pkpair(p[8], p[9]); d[3] = pkpair(p[10], p[11]);
  }
}

// one 32-edge tile: MLP + segmented key-max + leader store
__device__ __forceinline__ void mlp_tile(
    const float* __restrict__ x,
    const float* __restrict__ g1, const float* __restrict__ b1,
    const float* __restrict__ g2, const float* __restrict__ b2,
    const float* __restrict__ g3, const float* __restrict__ b3,
    const bf16x8* wfrag, unsigned short* __restrict__ pmax,
    int p, int vsrc, int vtgt, float wgt, int lane, int el, int g) {
  const float* xi = x + (size_t)vtgt * 64 + 8 * g;
  const float* xj = x + (size_t)vsrc * 64 + 8 * g;

  unsigned mp[32];
  float sum = 0.f, ssq = 0.f;
  #pragma unroll
  for (int t = 0; t < 4; ++t) {
    float4 a = *(const float4*)(xi + 16 * t);
    float4 b = *(const float4*)(xi + 16 * t + 4);
    float4 c = *(const float4*)(xj + 16 * t);
    float4 d4 = *(const float4*)(xj + 16 * t + 4);
    float lo[8] = {a.x, a.y, a.z, a.w, b.x, b.y, b.z, b.w};
    float up[8] = {wgt * (c.x - a.x), wgt * (c.y - a.y), wgt * (c.z - a.z), wgt * (c.w - a.w),
                   wgt * (d4.x - b.x), wgt * (d4.y - b.y), wgt * (d4.z - b.z), wgt * (d4.w - b.w)};
    #pragma unroll
    for (int pp = 0; pp < 4; ++pp) {
      mp[4 * t + pp] = pkpair(lo[2 * pp], lo[2 * pp + 1]);
      mp[16 + 4 * t + pp] = pkpair(up[2 * pp], up[2 * pp + 1]);
    }
    #pragma unroll
    for (int j = 0; j < 8; ++j) {
      sum += lo[j] + up[j];
      ssq += lo[j] * lo[j] + up[j] * up[j];
    }
  }

  sum += __shfl_xor(sum, 32);
  ssq += __shfl_xor(ssq, 32);
  const float mean1 = sum * (1.f / 128.f);
  const float rstd1 = rsqrtf(ssq * (1.f / 128.f) - mean1 * mean1 + 1e-5f);
  const float c01 = -mean1 * rstd1;

  U4 B1[8];
  #pragma unroll
  for (int t = 0; t < 8; ++t) {
    const int kb = ((t < 4) ? 16 * t : 64 + 16 * (t - 4)) + 8 * g;
    float4 ga = *(const float4*)(g1 + kb);
    float4 gb = *(const float4*)(g1 + kb + 4);
    float4 ba = *(const float4*)(b1 + kb);
    float4 bb = *(const float4*)(b1 + kb + 4);
    float gv[8] = {ga.x, ga.y, ga.z, ga.w, gb.x, gb.y, gb.z, gb.w};
    float bv[8] = {ba.x, ba.y, ba.z, ba.w, bb.x, bb.y, bb.z, bb.w};
    #pragma unroll
    for (int pp = 0; pp < 4; ++pp) {
      const unsigned u = mp[4 * t + pp];
      float v0 = fmaf(bflo(u), rstd1, c01);
      float v1 = fmaf(bfhi(u), rstd1, c01);
      v0 = fmaf(v0, gv[2 * pp], bv[2 * pp]);
      v1 = fmaf(v1, gv[2 * pp + 1], bv[2 * pp + 1]);
      v0 = fmaxf(v0, 0.2f * v0);
      v1 = fmaxf(v1, 0.2f * v1);
      B1[t].h[2 * pp] = (__bf16)v0;
      B1[t].h[2 * pp + 1] = (__bf16)v1;
    }
  }

  f32x16 A0, A1;
  #pragma unroll
  for (int i = 0; i < 16; ++i) { A0[i] = 0.f; A1[i] = 0.f; }
  #pragma unroll
  for (int t = 0; t < 8; ++t) {
    A0 = __builtin_amdgcn_mfma_f32_32x32x16_bf16(wfrag[(2 * t + 0) * 64 + lane], B1[t].v, A0, 0, 0, 0);
    A1 = __builtin_amdgcn_mfma_f32_32x32x16_bf16(wfrag[(2 * t + 1) * 64 + lane], B1[t].v, A1, 0, 0, 0);
  }

  float s2 = 0.f, q2 = 0.f;
  #pragma unroll
  for (int i = 0; i < 16; ++i) {
    s2 += A0[i] + A1[i];
    q2 += A0[i] * A0[i] + A1[i] * A1[i];
  }
  s2 += __shfl_xor(s2, 32); q2 += __shfl_xor(q2, 32);
  const float mean2 = s2 * (1.f / 64.f);
  const float rstd2 = rsqrtf(q2 * (1.f / 64.f) - mean2 * mean2 + 1e-5f);
  const float c02 = -mean2 * rstd2;

  U4 B2[4];
  #pragma unroll
  for (int t2 = 0; t2 < 4; ++t2) {
    const int kb = 16 * t2 + 4 * g;
    float4 gA = *(const float4*)(g2 + kb);
    float4 gB = *(const float4*)(g2 + kb + 8);
    float4 bA = *(const float4*)(b2 + kb);
    float4 bB = *(const float4*)(b2 + kb + 8);
    float gv[8] = {gA.x, gA.y, gA.z, gA.w, gB.x, gB.y, gB.z, gB.w};
    float bv[8] = {bA.x, bA.y, bA.z, bA.w, bB.x, bB.y, bB.z, bB.w};
    #pragma unroll
    for (int j = 0; j < 8; ++j) {
      const int reg = 4 * (2 * (t2 & 1) + (j >> 2)) + (j & 3);
      float v = (t2 >> 1) ? A1[reg] : A0[reg];
      v = fmaf(v, rstd2, c02);
      v = fmaf(v, gv[j], bv[j]);
      v = fmaxf(v, 0.2f * v);
      B2[t2].h[j] = (__bf16)v;
    }
  }

  #pragma unroll
  for (int i = 0; i < 16; ++i) { A0[i] = 0.f; A1[i] = 0.f; }
  #pragma unroll
  for (int t2 = 0; t2 < 4; ++t2) {
    A0 = __builtin_amdgcn_mfma_f32_32x32x16_bf16(wfrag[(16 + 2 * t2 + 0) * 64 + lane], B2[t2].v, A0, 0, 0, 0);
    A1 = __builtin_amdgcn_mfma_f32_32x32x16_bf16(wfrag[(16 + 2 * t2 + 1) * 64 + lane], B2[t2].v, A1, 0, 0, 0);
  }

  float s3 = 0.f, q3 = 0.f;
  #pragma unroll
  for (int i = 0; i < 16; ++i) {
    s3 += A0[i] + A1[i];
    q3 += A0[i] * A0[i] + A1[i] * A1[i];
  }
  s3 += __shfl_xor(s3, 32); q3 += __shfl_xor(q3, 32);
  const float mean3 = s3 * (1.f / 64.f);
  const float rstd3 = rsqrtf(q3 * (1.f / 64.f) - mean3 * mean3 + 1e-5f);
  const float c03 = -mean3 * rstd3;

  U4 B3[4];
  #pragma unroll
  for (int t2 = 0; t2 < 4; ++t2) {
    const int kb = 16 * t2 + 4 * g;
    float4 gA = *(const float4*)(g3 + kb);
    float4 gB = *(const float4*)(g3 + kb + 8);
    float4 bA = *(const float4*)(b3 + kb);
    float4 bB = *(const float4*)(b3 + kb + 8);
    float gv[8] = {gA.x, gA.y, gA.z, gA.w, gB.x, gB.y, gB.z, gB.w};
    float bv[8] = {bA.x, bA.y, bA.z, bA.w, bB.x, bB.y, bB.z, bB.w};
    #pragma unroll
    for (int j = 0; j < 8; ++j) {
      const int reg = 4 * (2 * (t2 & 1) + (j >> 2)) + (j & 3);
      float v = (t2 >> 1) ? A1[reg] : A0[reg];
      v = fmaf(v, rstd3, c03);
      v = fmaf(v, gv[j], bv[j]);
      v = fmaxf(v, 0.2f * v);
      B3[t2].h[j] = (__bf16)v;
    }
  }

  #pragma unroll
  for (int i = 0; i < 16; ++i) { A0[i] = 0.f; A1[i] = 0.f; }
  #pragma unroll
  for (int t2 = 0; t2 < 4; ++t2) {
    A0 = __builtin_amdgcn_mfma_f32_32x32x16_bf16(wfrag[(24 + 2 * t2 + 0) * 64 + lane], B3[t2].v, A0, 0, 0, 0);
    A1 = __builtin_amdgcn_mfma_f32_32x32x16_bf16(wfrag[(24 + 2 * t2 + 1) * 64 + lane], B3[t2].v, A1, 0, 0, 0);
  }

  unsigned P[16];
  #pragma unroll
  for (int q = 0; q < 4; ++q) {
    P[2 * q + 0] = pkpair(A0[4 * q + 0], A0[4 * q + 1]);
    P[2 * q + 1] = pkpair(A0[4 * q + 2], A0[4 * q + 3]);
    P[8 + 2 * q + 0] = pkpair(A1[4 * q + 0], A1[4 * q + 1]);
    P[8 + 2 * q + 1] = pkpair(A1[4 * q + 2], A1[4 * q + 3]);
  }
  #pragma unroll
  for (int i = 0; i < 16; ++i) {
    const unsigned u = P[i];
    const unsigned tt = (u >> 15) & 0x00010001u;
    P[i] = u ^ ((tt << 15) - tt + 0x80008000u);
  }
  int vt = vtgt;
  #pragma unroll
  for (int d = 1; d < 32; d <<= 1) {
    const int ot = __shfl_down(vt, d, 32);
    const bool mrg = (ot == vt);
    #pragma unroll
    for (int i = 0; i < 16; ++i) {
      const unsigned pv = __shfl_down(P[i], d, 32);
      const unsigned mx = pkmaxu16(P[i], pv);
      P[i] = mrg ? mx : P[i];
    }
  }
  const int pt = __shfl_up(vt, 1, 32);
  if (el == 0 || pt != vt) {
    unsigned short* row = pmax + (size_t)p * 64;
    #pragma unroll
    for (int q = 0; q < 4; ++q) {
      uint2 lo; lo.x = P[2 * q]; lo.y = P[2 * q + 1];
      uint2 hi; hi.x = P[8 + 2 * q]; hi.y = P[8 + 2 * q + 1];
      *(uint2*)(row + 8 * q + 4 * g) = lo;
      *(uint2*)(row + 32 + 8 * q + 4 * g) = hi;
    }
  }
}

// =========================== fused cooperative kernel ===========================

extern "C" __global__ void __launch_bounds__(256, 3)
mega_kernel(const float* __restrict__ x, const float* __restrict__ ew,
            const int* __restrict__ ei, const float* __restrict__ w1,
            const float* __restrict__ w2, const float* __restrict__ w3,
            const float* __restrict__ g1, const float* __restrict__ b1,
            const float* __restrict__ g2, const float* __restrict__ b2,
            const float* __restrict__ g3, const float* __restrict__ b3,
            unsigned* __restrict__ cnt, unsigned* __restrict__ partial,
            unsigned* __restrict__ base, unsigned* __restrict__ slot,
            uint2* __restrict__ srcw, unsigned short* __restrict__ pmax,
            float* __restrict__ out) {
  cg::grid_group grid = cg::this_grid();
  __shared__ unsigned lds_w[8192];
  __shared__ unsigned pscan[256];
  __shared__ unsigned wsum[4];

  const int tid = threadIdx.x;
  const int nblk = gridDim.x;
  const int gthread = blockIdx.x * 256 + tid;
  const int nthreads = nblk * 256;

  stage_weights(w1, w2, w3, lds_w, tid, 256);

  // phase 0: zero counters
  for (int i = gthread; i < NN; i += nthreads) cnt[i] = 0u;
  grid.sync();

  // phase 1: count + slot
  for (int e = gthread; e < NE; e += nthreads) {
    int t = ei[NE + e];
    t = min(max(t, 0), NN - 1);
    slot[e] = atomicAdd(cnt + t, 1u);
  }
  grid.sync();

  // phase 2: per-chunk sums
  if (blockIdx.x < PB) {
    const int wv = tid >> 6, ln = tid & 63;
    const int i = blockIdx.x * 256 + tid;
    unsigned v = (i < NN) ? cnt[i] : 0u;
    #pragma unroll
    for (int d = 1; d < 64; d <<= 1) v += (unsigned)__shfl_up((int)v, d) * (ln >= d ? 1u : 0u);
    if (ln == 63) wsum[wv] = v;
    __syncthreads();
    if (tid == 0) partial[blockIdx.x] = wsum[0] + wsum[1] + wsum[2] + wsum[3];
  }
  grid.sync();

  // phase 3: merged partial-scan + per-element scan -> base
  if (blockIdx.x < PB) {
    const int wv = tid >> 6, ln = tid & 63;
    const unsigned pv = (tid < PB) ? partial[tid] : 0u;
    unsigned s = pv;
    #pragma unroll
    for (int d = 1; d < 64; d <<= 1) s += (unsigned)__shfl_up((int)s, d) * (ln >= d ? 1u : 0u);
    if (ln == 63) wsum[wv] = s;
    __syncthreads();
    unsigned woff = 0;
    #pragma unroll
    for (int k = 0; k < 4; ++k) woff += (k < wv) ? wsum[k] : 0u;
    pscan[tid] = woff + s - pv;
    if (blockIdx.x == 0 && tid == 255) base[NN] = woff + s;
    __syncthreads();
    const unsigned blockoff = pscan[blockIdx.x];
    const int i = blockIdx.x * 256 + tid;
    const unsigned v = (i < NN) ? cnt[i] : 0u;
    unsigned s2 = v;
    #pragma unroll
    for (int d = 1; d < 64; d <<= 1) s2 += (unsigned)__shfl_up((int)s2, d) * (ln >= d ? 1u : 0u);
    if (ln == 63) wsum[wv] = s2;
    __syncthreads();
    unsigned woff2 = 0;
    #pragma unroll
    for (int k = 0; k < 4; ++k) woff2 += (k < wv) ? wsum[k] : 0u;
    if (i < NN) base[i] = blockoff + woff2 + s2 - v;
  }
  grid.sync();

  // phase 4: reorder records to CSR positions
  for (int e = gthread; e < NE; e += nthreads) {
    const int s = min(max(ei[e], 0), NN - 1);
    const int t = min(max(ei[NE + e], 0), NN - 1);
    const unsigned pos = base[t] + slot[e];
    uint2 rec;
    rec.x = (unsigned)s | ((unsigned)t << 16);
    rec.y = __float_as_uint(ew[e]);
    srcw[pos] = rec;
  }
  grid.sync();

  // phase 5: edge MLP
  {
    const int lane = tid & 63;
    const int el = lane & 31;
    const int g = lane >> 5;
    const bf16x8* wfrag = (const bf16x8*)lds_w;
    const int wid = blockIdx.x * 4 + (tid >> 6);
    const int nw = nblk * 4;

    int tile = wid;
    int pvs = 0, pvt = 0; float pw = 0.f;
    if (tile < NT) {
      const uint2 rec = srcw[tile * 32 + el];
      pvs = (int)(rec.x & 0xFFFFu); pvt = (int)(rec.x >> 16); pw = __uint_as_float(rec.y);
    }
    while (tile < NT) {
      asm volatile("" ::: "memory");
      const int p = tile * 32 + el;
      const int vsrc = pvs, vtgt = pvt;
      const float wgt = pw;
      const int ntile = tile + nw;
      if (ntile < NT) {
        const uint2 rec = srcw[ntile * 32 + el];
        pvs = (int)(rec.x & 0xFFFFu); pvt = (int)(rec.x >> 16); pw = __uint_as_float(rec.y);
      }
      mlp_tile(x, g1, b1, g2, b2, g3, b3, wfrag, pmax, p, vsrc, vtgt, wgt, lane, el, g);
      tile = ntile;
    }
  }
  grid.sync();

  // phase 6: gather max + residual
  {
    const int lane = tid & 63;
    const int gwave = blockIdx.x * 4 + (tid >> 6);
    const int nwave = nblk * 4;
    for (int node = gwave; node < NN; node += nwave) {
      const unsigned b0 = base[node];
      const unsigned b1v = base[node + 1];
      float maxv = 0.f;
      if (b1v > b0) {
        unsigned kmax = pmax[(size_t)b0 * 64 + lane];
        const unsigned k1 = (b1v - 1) >> 5;
        for (unsigned k = (b0 >> 5) + 1; k <= k1; ++k) {
          kmax = max(kmax, (unsigned)pmax[((size_t)k << 5) * 64 + lane]);
        }
        const unsigned orig = (kmax & 0x8000u) ? (kmax ^ 0x8000u) : (~kmax & 0xFFFFu);
        maxv = __uint_as_float(orig << 16);
      }
      const size_t o = (size_t)node * 64 + lane;
      out[o] = maxv + x[o];
    }
  }
}

// =========================== fallback pipeline (R9, proven) ===========================

extern "C" __global__ void __launch_bounds__(256)
scatter_kernel(const int* __restrict__ ei, unsigned* __restrict__ cnt,
               unsigned* __restrict__ slot) {
  const int e = blockIdx.x * 256 + threadIdx.x;
  if (e < NE) {
    int t = ei[NE + e];
    t = min(max(t, 0), NN - 1);
    slot[e] = atomicAdd(cnt + t, 1u);
  }
}

extern "C" __global__ void __launch_bounds__(256)
scan_a_kernel(const unsigned* __restrict__ cnt, unsigned* __restrict__ partial) {
  __shared__ unsigned wsum[4];
  const int t = threadIdx.x, wv = t >> 6, ln = t & 63;
  const int i = blockIdx.x * 256 + t;
  unsigned v = (i < NN) ? cnt[i] : 0u;
  #pragma unroll
  for (int d = 1; d < 64; d <<= 1) v += (unsigned)__shfl_up((int)v, d) * (ln >= d ? 1u : 0u);
  if (ln == 63) wsum[wv] = v;
  __syncthreads();
  if (t == 0) partial[blockIdx.x] = wsum[0] + wsum[1] + wsum[2] + wsum[3];
}

extern "C" __global__ void __launch_bounds__(256)
scan_c_kernel(const unsigned* __restrict__ cnt, const unsigned* __restrict__ partial,
              unsigned* __restrict__ base) {
  __shared__ unsigned pscan[256];
  __shared__ unsigned wsum[4];
  const int t = threadIdx.x, wv = t >> 6, ln = t & 63;
  const unsigned pv = (t < PB) ? partial[t] : 0u;
  unsigned s = pv;
  #pragma unroll
  for (int d = 1; d < 64; d <<= 1) s += (unsigned)__shfl_up((int)s, d) * (ln >= d ? 1u : 0u);
  if (ln == 63) wsum[wv] = s;
  __syncthreads();
  unsigned woff = 0;
  #pragma unroll
  for (int k = 0; k < 4; ++k) woff += (k < wv) ? wsum[k] : 0u;
  pscan[t] = woff + s - pv;
  if (blockIdx.x == 0 && t == 255) base[NN] = woff + s;
  __syncthreads();
  const unsigned blockoff = pscan[blockIdx.x];
  const int i = blockIdx.x * 256 + t;
  const unsigned v = (i < NN) ? cnt[i] : 0u;
  unsigned s2 = v;
  #pragma unroll
  for (int d = 1; d < 64; d <<= 1) s2 += (unsigned)__shfl_up((int)s2, d) * (ln >= d ? 1u : 0u);
  if (ln == 63) wsum[wv] = s2;
  __syncthreads();
  unsigned woff2 = 0;
  #pragma unroll
  for (int k = 0; k < 4; ++k) woff2 += (k < wv) ? wsum[k] : 0u;
  if (i < NN) base[i] = blockoff + woff2 + s2 - v;
}

extern "C" __global__ void __launch_bounds__(256)
reorder_kernel(const int* __restrict__ ei, const float* __restrict__ ew,
               const unsigned* __restrict__ base, const unsigned* __restrict__ slot,
               uint2* __restrict__ srcw) {
  const int e = blockIdx.x * 256 + threadIdx.x;
  if (e < NE) {
    const int s = min(max(ei[e], 0), NN - 1);
    const int t = min(max(ei[NE + e], 0), NN - 1);
    const unsigned pos = base[t] + slot[e];
    uint2 rec;
    rec.x = (unsigned)s | ((unsigned)t << 16);
    rec.y = __float_as_uint(ew[e]);
    srcw[pos] = rec;
  }
}

extern "C" __global__ void __launch_bounds__(256, 3)
edge_mlp_kernel(const float* __restrict__ x, const float* __restrict__ w1,
                const float* __restrict__ w2, const float* __restrict__ w3,
                const float* __restrict__ g1, const float* __restrict__ b1,
                const float* __restrict__ g2, const float* __restrict__ b2,
                const float* __restrict__ g3, const float* __restrict__ b3,
                const uint2* __restrict__ srcw,
                unsigned short* __restrict__ pmax) {
  __shared__ unsigned lds_w[8192];
  const int tid = threadIdx.x;
  stage_weights(w1, w2, w3, lds_w, tid, 256);
  __syncthreads();

  const int lane = tid & 63;
  const int el = lane & 31;
  const int g = lane >> 5;
  const bf16x8* wfrag = (const bf16x8*)lds_w;
  const int wid = blockIdx.x * 4 + (tid >> 6);
  const int nw = gridDim.x * 4;

  int tile = wid;
  int pvs = 0, pvt = 0; float pw = 0.f;
  if (tile < NT) {
    const uint2 rec = srcw[tile * 32 + el];
    pvs = (int)(rec.x & 0xFFFFu); pvt = (int)(rec.x >> 16); pw = __uint_as_float(rec.y);
  }
  while (tile < NT) {
    asm volatile("" ::: "memory");
    const int p = tile * 32 + el;
    const int vsrc = pvs, vtgt = pvt;
    const float wgt = pw;
    const int ntile = tile + nw;
    if (ntile < NT) {
      const uint2 rec = srcw[ntile * 32 + el];
      pvs = (int)(rec.x & 0xFFFFu); pvt = (int)(rec.x >> 16); pw = __uint_as_float(rec.y);
    }
    mlp_tile(x, g1, b1, g2, b2, g3, b3, wfrag, pmax, p, vsrc, vtgt, wgt, lane, el, g);
    tile = ntile;
  }
}

extern "C" __global__ void __launch_bounds__(256)
gather_max_kernel(const float* __restrict__ x, const unsigned short* __restrict__ pmax,
                  const unsigned* __restrict__ base, float* __restrict__ out) {
  const int node = blockIdx.x * 4 + (threadIdx.x >> 6);
  const int lane = threadIdx.x & 63;
  if (node >= NN) return;
  const unsigned b0 = base[node];
  const unsigned b1v = base[node + 1];
  float maxv = 0.f;
  if (b1v > b0) {
    unsigned kmax = pmax[(size_t)b0 * 64 + lane];
    const unsigned k1 = (b1v - 1) >> 5;
    for (unsigned k = (b0 >> 5) + 1; k <= k1; ++k) {
      kmax = max(kmax, (unsigned)pmax[((size_t)k << 5) * 64 + lane]);
    }
    const unsigned orig = (kmax & 0x8000u) ? (kmax ^ 0x8000u) : (~kmax & 0xFFFFu);
    maxv = __uint_as_float(orig << 16);
  }
  const size_t o = (size_t)node * 64 + lane;
  out[o] = maxv + x[o];
}

// =========================== host launcher ===========================

extern "C" void kernel_launch(void* const* d_in, const int* in_sizes, int n_in,
                              void* d_out, int out_size, void* d_ws, size_t ws_size,
                              hipStream_t stream) {
  (void)in_sizes; (void)n_in; (void)out_size; (void)ws_size;
  const float* x  = (const float*)d_in[0];
  const float* ew = (const float*)d_in[1];
  const int*   ei = (const int*)d_in[2];
  const float* w1 = (const float*)d_in[3];
  const float* w2 = (const float*)d_in[4];
  const float* w3 = (const float*)d_in[5];
  const float* g1 = (const float*)d_in[6];
  const float* b1 = (const float*)d_in[7];
  const float* g2 = (const float*)d_in[8];
  const float* b2 = (const float*)d_in[9];
  const float* g3 = (const float*)d_in[10];
  const float* b3 = (const float*)d_in[11];

  unsigned* cnt  = (unsigned*)((char*)d_ws + CNT_OFF);
  unsigned* base = (unsigned*)((char*)d_ws + BASE_OFF);
  unsigned* part = (unsigned*)((char*)d_ws + PART_OFF);
  unsigned* slot = (unsigned*)((char*)d_ws + SLOT_OFF);
  uint2*    srcw = (uint2*)((char*)d_ws + SRCW_OFF);
  unsigned short* pmax = (unsigned short*)((char*)d_ws + M_OFF);
  float* out = (float*)d_out;

  // size the cooperative grid from actual achievable residency
  int blocksPerCU = 0;
  hipError_t qerr = hipOccupancyMaxActiveBlocksPerMultiprocessor(
      &blocksPerCU, (const void*)mega_kernel, 256, 0);
  int nblk = (qerr == hipSuccess) ? blocksPerCU * 256 : 0;

  hipError_t lerr = hipErrorUnknown;
  if (nblk >= 256) {  // need >= PB blocks for the scan phases
    void* args[] = {
      (void*)&x, (void*)&ew, (void*)&ei, (void*)&w1, (void*)&w2, (void*)&w3,
      (void*)&g1, (void*)&b1, (void*)&g2, (void*)&b2, (void*)&g3, (void*)&b3,
      (void*)&cnt, (void*)&part, (void*)&base, (void*)&slot,
      (void*)&srcw, (void*)&pmax, (void*)&out
    };
    lerr = hipLaunchCooperativeKernel((void*)mega_kernel, dim3(nblk), dim3(256),
                                      args, 0, stream);
  }

  if (lerr != hipSuccess) {
    // fallback: proven 7-launch pipeline
    hipMemsetAsync(cnt, 0, (size_t)NN * sizeof(unsigned), stream);
    scatter_kernel<<<(NE + 255) / 256, 256, 0, stream>>>(ei, cnt, slot);
    scan_a_kernel<<<PB, 256, 0, stream>>>(cnt, part);
    scan_c_kernel<<<PB, 256, 0, stream>>>(cnt, part, base);
    reorder_kernel<<<(NE + 255) / 256, 256, 0, stream>>>(ei, ew, base, slot, srcw);
    edge_mlp_kernel<<<3125, 256, 0, stream>>>(x, w1, w2, w3,
                                              g1, b1, g2, b2, g3, b3, srcw, pmax);
    gather_max_kernel<<<(NN + 3) / 4, 256, 0, stream>>>(x, pmax, base, out);
  }
}